// Round 1
// 582.258 us; speedup vs baseline: 1.0276x; 1.0276x over previous
//
#include <hip/hip_runtime.h>
#include <math.h>

// Problem: B=16, C=512, R=32, PS=3, HN=8, D=128, H=W=96.
typedef unsigned short u16;
typedef short bf16x8 __attribute__((ext_vector_type(8)));
typedef float floatx4 __attribute__((ext_vector_type(4)));
typedef unsigned short ushort4v __attribute__((ext_vector_type(4)));

// ---- workspace layout ----
// floats:
#define F_QP   0ull            // [b][c=512][r=1024] fp32 pooled avg (residual + src)
#define F_IPW  8388608ull      // [bh][512]
#define F_WPT  8454144ull      // WpT [c][c2] 512x512
#define F_END  8716288ull
// ushorts (base = (u16*)(ws + F_END)):
#define U_QPT_V 0ull           // [b][r=1024][c=512]
#define U_QPT_P 8388608ull     // [b][cc=512][s=1024]
#define U_KPT_P 16777216ull
#define U_PQ    25165824ull    // [bh][c=512][e=128]
#define U_PK    33554432ull
#define U_VP    41943040ull    // [b] flat [o=512][r=1024]
#define U_WV    50331648ull
#define U_WQK   50593792ull

__device__ __forceinline__ u16 f2bf(float f) {
    union { float f; unsigned u; } v; v.f = f;
    return (u16)((v.u + 0x7fffu + ((v.u >> 16) & 1u)) >> 16);
}
__device__ __forceinline__ float bf2f(u16 u) {
    union { unsigned u; float f; } v; v.u = ((unsigned)u) << 16;
    return v.f;
}
__device__ __forceinline__ void ld_async16(const u16* g, u16* l) {
    __builtin_amdgcn_global_load_lds(
        (const __attribute__((address_space(1))) void*)g,
        (__attribute__((address_space(3))) void*)l, 16, 0, 0);
}

// ---------------- K1: fused 3x3 avg+max pool + bf16 transposes ----------------
// v2: stage the 32ch x 3row x 96col slab in LDS via coalesced float4 loads
// (9 per thread), then pool from LDS. Pool math order bit-identical to v1.
__global__ __launch_bounds__(256) void pool_fused(const float* __restrict__ x,
                                                  float* __restrict__ qp,
                                                  u16* __restrict__ qpT_v,
                                                  u16* __restrict__ qpT_p,
                                                  u16* __restrict__ kpT_p) {
    __shared__ __align__(16) float Xs[9216];   // [ch=32][288] (3 contiguous rows)
    __shared__ float Tq[32][33], Tk[32][33];
    const int tid = threadIdx.x;
    const int i  = blockIdx.x;        // pooled row 0..31
    const int c0 = blockIdx.y * 32;   // channel base
    const int b  = blockIdx.z;
    {   // stage: 2304 float4, fully coalesced (each channel's 3 rows contiguous)
        const float* xb = x + (size_t)b * 4718592 + (size_t)c0 * 9216 + (3 * i) * 96;
        float4* Xs4 = (float4*)Xs;
        #pragma unroll
        for (int it = 0; it < 9; ++it) {
            int f = tid + it * 256;          // 0..2303
            int cl = f / 72;                 // channel 0..31
            int rem = f - cl * 72;           // float4 within 288-float segment
            Xs4[f] = *(const float4*)(xb + (size_t)cl * 9216 + rem * 4);
        }
    }
    __syncthreads();
    const int j = tid & 31, cg = tid >> 5;
    #pragma unroll
    for (int p = 0; p < 4; ++p) {
        int cl = p * 8 + cg;
        const float* px = Xs + cl * 288 + 3 * j;   // stride-3 lanes: gcd(3,32)=1, no conflict
        float s = 0.f, mx = -INFINITY;
        #pragma unroll
        for (int di = 0; di < 3; ++di)
            #pragma unroll
            for (int dj = 0; dj < 3; ++dj) {
                float v = px[di * 96 + dj];
                s += v; mx = fmaxf(mx, v);
            }
        float q = s * (1.f / 9.f);
        Tq[cl][j] = q; Tk[cl][j] = mx;
        qp[(size_t)b * 524288 + (size_t)(c0 + cl) * 1024 + i * 32 + j] = q;
    }
    __syncthreads();
    const int cl = tid & 31, jq = tid >> 5;
    const int rh = i >> 4;
    const int s2 = (c0 + cl) * 2 + rh;
    #pragma unroll
    for (int jj = 0; jj < 4; ++jj) {
        int jw = jq + jj * 8;
        int rr = i * 32 + jw;
        int cc = rr & 511;
        u16 qb = f2bf(Tq[cl][jw]);
        u16 kb = f2bf(Tk[cl][jw]);
        qpT_v[(size_t)b * 524288 + (size_t)rr * 512 + c0 + cl] = qb;
        qpT_p[(size_t)b * 524288 + (size_t)cc * 1024 + s2] = qb;
        kpT_p[(size_t)b * 524288 + (size_t)cc * 1024 + s2] = kb;
    }
}

// ---------------- K2: weight prep (casts + Wp transpose) in ONE launch ----------------
// blocks 0..383: float4->ushort4 cast of Wv (262144 f) then Wqk (131072 f).
// blocks 384..639: 32x32 transpose tiles of Wp into WpT.
__global__ __launch_bounds__(256) void prep_w(const float* __restrict__ Wv,
                                              const float* __restrict__ Wqk,
                                              const float* __restrict__ Wp,
                                              u16* __restrict__ Wv_bf,
                                              u16* __restrict__ Wqk_bf,
                                              float* __restrict__ WpT) {
    __shared__ float t[32][33];
    const int blk = blockIdx.x, tid = threadIdx.x;
    if (blk < 384) {
        int i = (blk * 256 + tid) * 4;
        const float* src; u16* dst; int off;
        if (i < 262144) { src = Wv; dst = Wv_bf; off = i; }
        else            { src = Wqk; dst = Wqk_bf; off = i - 262144; }
        float4 v = *(const float4*)(src + off);
        ushort4v o; o.x = f2bf(v.x); o.y = f2bf(v.y); o.z = f2bf(v.z); o.w = f2bf(v.w);
        *(ushort4v*)(dst + off) = o;
    } else {
        int bb = blk - 384;
        int x0 = (bb & 15) * 32, y0 = (bb >> 4) * 32;
        int tx = tid & 31, ty = tid >> 5;
        #pragma unroll
        for (int it = 0; it < 4; ++it)
            t[ty + it * 8][tx] = Wp[(size_t)(y0 + ty + it * 8) * 512 + x0 + tx];
        __syncthreads();
        #pragma unroll
        for (int it = 0; it < 4; ++it)
            WpT[(size_t)(x0 + ty + it * 8) * 512 + y0 + tx] = t[tx][ty + it * 8];
    }
}

// ---------------- shared MFMA 128x128 BT-GEMM body (m97 structure) ----------------
__device__ __forceinline__ void gemm_bt_body(const u16* __restrict__ A, int ldA,
                                             const u16* __restrict__ B, int ldB, int K,
                                             u16* As, u16* Bs, floatx4 (&acc)[4][4]) {
    const int tid = threadIdx.x;
    const int lane = tid & 63;
    const int wv = tid >> 6;
    const int wm = (wv & 1) * 64, wn = (wv >> 1) * 64;
    const u16* ga0 = A + (size_t)(tid >> 2) * ldA + (tid & 3) * 8;
    const u16* ga1 = A + (size_t)((tid >> 2) + 64) * ldA + (tid & 3) * 8;
    const u16* gb0 = B + (size_t)(tid >> 2) * ldB + (tid & 3) * 8;
    const u16* gb1 = B + (size_t)((tid >> 2) + 64) * ldB + (tid & 3) * 8;
    u16* la0 = As + tid * 8;
    u16* la1 = As + (tid + 256) * 8;
    u16* lb0 = Bs + tid * 8;
    u16* lb1 = Bs + (tid + 256) * 8;
    const int arow = (lane & 15) * 32 + (lane >> 4) * 8;
    for (int k0 = 0; k0 < K; k0 += 32) {
        ld_async16(ga0 + k0, la0);
        ld_async16(ga1 + k0, la1);
        ld_async16(gb0 + k0, lb0);
        ld_async16(gb1 + k0, lb1);
        __syncthreads();
        bf16x8 af[4], bfr[4];
        #pragma unroll
        for (int i = 0; i < 4; ++i)
            af[i] = *(const bf16x8*)&As[(wm + i * 16) * 32 + arow];
        #pragma unroll
        for (int j = 0; j < 4; ++j)
            bfr[j] = *(const bf16x8*)&Bs[(wn + j * 16) * 32 + arow];
        #pragma unroll
        for (int i = 0; i < 4; ++i)
            #pragma unroll
            for (int j = 0; j < 4; ++j)
                acc[i][j] = __builtin_amdgcn_mfma_f32_16x16x32_bf16(af[i], bfr[j], acc[i][j], 0, 0, 0);
        __syncthreads();
    }
}

// ---------------- K3: merged GEMMs (vpool + proj) in ONE launch ----------------
// blocks 0..511: vp[o][r] = bv[o] + sum_c Wv[o][c]*qpool[c][r]   (512 = 8n x 4m x 16b)
// blocks 512..1535: proj[c][e] = bqk[h][e] + sum_d headsT[c][d]*Wqk[h][e][d]
__global__ __launch_bounds__(256) void gemms_mfma(const u16* __restrict__ Wv_bf,
                                                  const float* __restrict__ bv,
                                                  const u16* __restrict__ qpT_v,
                                                  u16* __restrict__ vp_bf,
                                                  const u16* __restrict__ qpT_p,
                                                  const u16* __restrict__ kpT_p,
                                                  const u16* __restrict__ Wqk_bf,
                                                  const float* __restrict__ bqk,
                                                  u16* __restrict__ pq_bf,
                                                  u16* __restrict__ pk_bf) {
    __shared__ __align__(16) u16 As[4096], Bs[4096];
    floatx4 acc[4][4] = {};
    const int tid = threadIdx.x, lane = tid & 63, wv = tid >> 6;
    const int wm = (wv & 1) * 64, wn = (wv >> 1) * 64, col = lane & 15, quad = lane >> 4;
    const int blk = blockIdx.x;
    if (blk < 512) {
        const int n0 = (blk & 7) * 128, m0 = ((blk >> 3) & 3) * 128, b = blk >> 5;
        gemm_bt_body(Wv_bf + (size_t)m0 * 512, 512,
                     qpT_v + (size_t)b * 524288 + (size_t)n0 * 512, 512, 512, As, Bs, acc);
        u16* outb = vp_bf + (size_t)b * 524288;
        #pragma unroll
        for (int i = 0; i < 4; ++i)
            #pragma unroll
            for (int r = 0; r < 4; ++r) {
                int m = m0 + wm + i * 16 + quad * 4 + r;
                float bias = bv[m];
                #pragma unroll
                for (int j = 0; j < 4; ++j) {
                    int n = n0 + wn + j * 16 + col;
                    outb[(size_t)m * 1024 + n] = f2bf(acc[i][j][r] + bias);
                }
            }
    } else {
        const int blk2 = blk - 512;
        const int m0 = (blk2 & 3) * 128;
        const int z = blk2 >> 2;
        const int b = z >> 4, h = (z >> 1) & 7, src = z & 1;
        const u16* P = (src ? kpT_p : qpT_p) + (size_t)b * 524288 + (size_t)m0 * 1024 + h * 128;
        gemm_bt_body(P, 1024, Wqk_bf + h * 16384, 128, 128, As, Bs, acc);
        u16* outp = (src ? pk_bf : pq_bf) + (size_t)(b * 8 + h) * 65536 + (size_t)m0 * 128;
        #pragma unroll
        for (int i = 0; i < 4; ++i)
            #pragma unroll
            for (int r = 0; r < 4; ++r) {
                int m = wm + i * 16 + quad * 4 + r;
                #pragma unroll
                for (int j = 0; j < 4; ++j) {
                    int n = wn + j * 16 + col;
                    outp[(size_t)m * 128 + n] = f2bf(acc[i][j][r] + bqk[h * 128 + n]);
                }
            }
    }
}

// ---------------- K4: fused kbar -> mrow -> gate (per bh), vectorized ----------------
__global__ __launch_bounds__(256) void gate_fused(const u16* __restrict__ pq_bf,
                                                  const u16* __restrict__ pk_bf,
                                                  const float* __restrict__ WpT,
                                                  const float* __restrict__ bp,
                                                  float* __restrict__ ipw) {
    __shared__ float red[16][128];   // rowgroup partials
    __shared__ float kb[128];
    __shared__ float ms[512];
    const int bh = blockIdx.x, tid = threadIdx.x;
    const u16* pkb = pk_bf + (size_t)bh * 65536;
    const u16* pqb = pq_bf + (size_t)bh * 65536;
    {   // kbar partials: 16 d-chunks x 16 rowgroups, bf16x8 loads (16B/lane, coalesced)
        const int dc = tid & 15, rg = tid >> 4;
        float a[8] = {};
        const u16* p = pkb + (size_t)rg * 4096 + dc * 8;   // rg*32 rows * 128
        #pragma unroll 8
        for (int r = 0; r < 32; ++r) {
            bf16x8 v = *(const bf16x8*)(p + (size_t)r * 128);
            #pragma unroll
            for (int k = 0; k < 8; ++k) a[k] += bf2f((u16)v[k]);
        }
        #pragma unroll
        for (int k = 0; k < 8; ++k) red[rg][dc * 8 + k] = a[k];
    }
    __syncthreads();
    if (tid < 128) {
        float s = 0.f;
        #pragma unroll
        for (int g = 0; g < 16; ++g) s += red[g][tid];
        kb[tid] = s * (1.f / 512.f);
    }
    __syncthreads();
    // mrow: ms[cc] = dot(pq[cc][:], kb)
    for (int cc = tid; cc < 512; cc += 256) {
        const u16* q = pqb + (size_t)cc * 128;
        float s = 0.f;
        #pragma unroll
        for (int ch = 0; ch < 16; ++ch) {
            bf16x8 v = *(const bf16x8*)(q + ch * 8);
            #pragma unroll
            for (int k = 0; k < 8; ++k) s += bf2f((u16)v[k]) * kb[ch * 8 + k];
        }
        ms[cc] = s;
    }
    __syncthreads();
    {   // gate matvec: float2 loads, dual accumulators
        const int c2 = tid * 2;
        float a0 = bp[c2], a1 = bp[c2 + 1];
        #pragma unroll 4
        for (int c = 0; c < 512; ++c) {
            float m = ms[c];
            float2 w = *(const float2*)&WpT[(size_t)c * 512 + c2];
            a0 += m * w.x; a1 += m * w.y;
        }
        float p0 = 1.f / (1.f + __expf(-a0));
        float p1 = 1.f / (1.f + __expf(-a1));
        ipw[bh * 512 + c2]     = exp2f(-7.f * (0.5f + p0));   // 128^-(0.5+p)
        ipw[bh * 512 + c2 + 1] = exp2f(-7.f * (0.5f + p1));
    }
}

// ---------------- K5: flash-fused scores->exp->rowsum->PV->residual ----------------
// Block: (m0 c-slice of 128, bh). e-tile kept in LDS; out[d][c] orientation (coalesced).
__global__ __launch_bounds__(256, 2) void flash_mfma(const u16* __restrict__ pq_bf,
                                                     const u16* __restrict__ pk_bf,
                                                     const u16* __restrict__ vp_bf,
                                                     const float* __restrict__ ipw,
                                                     const float* __restrict__ qp,
                                                     float* __restrict__ outp,
                                                     const int* __restrict__ wgt) {
    __shared__ __align__(16) u16 As[4096];
    __shared__ __align__(16) u16 Bs[4096];
    __shared__ __align__(16) u16 Et[128 * 136];
    __shared__ float rsS[128];
    __shared__ float ipwS[128];
    const int tid = threadIdx.x, lane = tid & 63, wv = tid >> 6;
    const int wm = (wv & 1) * 64, wn = (wv >> 1) * 64, col = lane & 15, quad = lane >> 4;
    const int bh = blockIdx.y, b = bh >> 3, h = bh & 7;
    const int m0 = blockIdx.x * 128;
    if (tid < 128) { rsS[tid] = 0.f; ipwS[tid] = ipw[bh * 512 + m0 + tid]; }
    const u16* Aq = pq_bf + (size_t)bh * 65536 + (size_t)m0 * 128;
    const u16* Bk = pk_bf + (size_t)bh * 65536;
    const u16* Av = vp_bf + (size_t)b * 524288 + (size_t)h * 65536;
    const int srow = tid >> 2, scol = (tid & 3) * 8;
    u16 *la0 = As + tid * 8, *la1 = As + (tid + 256) * 8;
    u16 *lb0 = Bs + tid * 8, *lb1 = Bs + (tid + 256) * 8;
    const int arow = col * 32 + quad * 8;
    floatx4 accP[4][4] = {};
    __syncthreads();

    for (int n0 = 0; n0 < 512; n0 += 128) {
        // ---- score GEMM (rows c, cols e-chunk), K=128 ----
        floatx4 accS[4][4] = {};
        for (int k0 = 0; k0 < 128; k0 += 32) {
            ld_async16(Aq + (size_t)srow * 128 + k0 + scol, la0);
            ld_async16(Aq + (size_t)(srow + 64) * 128 + k0 + scol, la1);
            ld_async16(Bk + (size_t)(n0 + srow) * 128 + k0 + scol, lb0);
            ld_async16(Bk + (size_t)(n0 + srow + 64) * 128 + k0 + scol, lb1);
            __syncthreads();
            bf16x8 af[4], bfr[4];
            #pragma unroll
            for (int i = 0; i < 4; ++i) af[i] = *(const bf16x8*)&As[(wm + i * 16) * 32 + arow];
            #pragma unroll
            for (int j = 0; j < 4; ++j) bfr[j] = *(const bf16x8*)&Bs[(wn + j * 16) * 32 + arow];
            #pragma unroll
            for (int i = 0; i < 4; ++i)
                #pragma unroll
                for (int j = 0; j < 4; ++j)
                    accS[i][j] = __builtin_amdgcn_mfma_f32_16x16x32_bf16(af[i], bfr[j], accS[i][j], 0, 0, 0);
            __syncthreads();
        }
        // ---- epilogue: exp -> Et (LDS), rowsum -> rsS ----
        #pragma unroll
        for (int i = 0; i < 4; ++i)
            #pragma unroll
            for (int r = 0; r < 4; ++r) {
                int ml = wm + i * 16 + quad * 4 + r;
                float sc = ipwS[ml];
                float p = 0.f;
                #pragma unroll
                for (int j = 0; j < 4; ++j) {
                    float e = __expf(accS[i][j][r] * sc);
                    p += e;
                    Et[ml * 136 + wn + j * 16 + col] = f2bf(e);
                }
                #pragma unroll
                for (int o = 8; o; o >>= 1) p += __shfl_xor(p, o);
                if (col == 0) atomicAdd(&rsS[ml], p);
            }
        __syncthreads();
        // ---- PV partial: A = v (rows d), B = Et (rows c), K = 128 ----
        for (int k0 = 0; k0 < 128; k0 += 32) {
            ld_async16(Av + (size_t)srow * 512 + n0 + k0 + scol, la0);
            ld_async16(Av + (size_t)(srow + 64) * 512 + n0 + k0 + scol, la1);
            __syncthreads();
            bf16x8 af[4], bfr[4];
            #pragma unroll
            for (int i = 0; i < 4; ++i) af[i] = *(const bf16x8*)&As[(wm + i * 16) * 32 + arow];
            #pragma unroll
            for (int j = 0; j < 4; ++j) bfr[j] = *(const bf16x8*)&Et[(wn + j * 16 + col) * 136 + k0 + quad * 8];
            #pragma unroll
            for (int i = 0; i < 4; ++i)
                #pragma unroll
                for (int j = 0; j < 4; ++j)
                    accP[i][j] = __builtin_amdgcn_mfma_f32_16x16x32_bf16(af[i], bfr[j], accP[i][j], 0, 0, 0);
            __syncthreads();
        }
    }
    const float mult = 1.f + (float)wgt[0];
    #pragma unroll
    for (int j = 0; j < 4; ++j) {
        int nl = wn + j * 16 + col;                 // c local
        float inv = mult / rsS[nl];
        #pragma unroll
        for (int i = 0; i < 4; ++i)
            #pragma unroll
            for (int r = 0; r < 4; ++r) {
                int d = wm + i * 16 + quad * 4 + r;
                size_t o = (size_t)b * 524288 + (size_t)(h * 128 + d) * 512 + m0 + nl;
                outp[o] = qp[o] + accP[i][j][r] * inv;
            }
    }
}

extern "C" void kernel_launch(void* const* d_in, const int* in_sizes, int n_in,
                              void* d_out, int out_size, void* d_ws, size_t ws_size,
                              hipStream_t stream) {
    const float* x   = (const float*)d_in[0];
    const float* Wqk = (const float*)d_in[1];
    const float* bqk = (const float*)d_in[2];
    const float* Wp  = (const float*)d_in[3];
    const float* bp  = (const float*)d_in[4];
    const float* Wv  = (const float*)d_in[5];
    const float* bv  = (const float*)d_in[6];
    const int*   wgt = (const int*)d_in[7];
    float* out = (float*)d_out;

    float* ws = (float*)d_ws;
    float* qp  = ws + F_QP;
    float* ipw = ws + F_IPW;
    float* WpT = ws + F_WPT;
    u16* ub = (u16*)(ws + F_END);
    u16* qpT_v  = ub + U_QPT_V;
    u16* qpT_p  = ub + U_QPT_P;
    u16* kpT_p  = ub + U_KPT_P;
    u16* pq_bf  = ub + U_PQ;
    u16* pk_bf  = ub + U_PK;
    u16* vp_bf  = ub + U_VP;
    u16* Wv_bf  = ub + U_WV;
    u16* Wqk_bf = ub + U_WQK;

    prep_w<<<640, 256, 0, stream>>>(Wv, Wqk, Wp, Wv_bf, Wqk_bf, WpT);
    pool_fused<<<dim3(32, 16, 16), 256, 0, stream>>>(x, qp, qpT_v, qpT_p, kpT_p);
    gemms_mfma<<<1536, 256, 0, stream>>>(Wv_bf, bv, qpT_v, vp_bf,
                                         qpT_p, kpT_p, Wqk_bf, bqk, pq_bf, pk_bf);
    gate_fused<<<128, 256, 0, stream>>>(pq_bf, pk_bf, WpT, bp, ipw);
    flash_mfma<<<dim3(4, 128), 256, 0, stream>>>(pq_bf, pk_bf, vp_bf, ipw, qp, out, wgt);
}

// Round 3
// 534.094 us; speedup vs baseline: 1.1203x; 1.0902x over previous
//
#include <hip/hip_runtime.h>
#include <math.h>

// Problem: B=16, C=512, R=32, PS=3, HN=8, D=128, H=W=96.
typedef unsigned short u16;
typedef short bf16x8 __attribute__((ext_vector_type(8)));
typedef float floatx4 __attribute__((ext_vector_type(4)));
typedef unsigned short ushort4v __attribute__((ext_vector_type(4)));

// ---- workspace layout ----
// floats:
#define F_QP   0ull            // [b][c=512][r=1024] fp32 pooled avg (residual + src)
#define F_IPW  8388608ull      // [bh][512]
#define F_WPT  8454144ull      // WpT [c][c2] 512x512
#define F_END  8716288ull
// ushorts (base = (u16*)(ws + F_END)):
#define U_QPT_V 0ull           // [b][r=1024][c=512]
#define U_QPT_P 8388608ull     // [b][cc=512][s=1024]
#define U_KPT_P 16777216ull
#define U_PQ    25165824ull    // [bh][c=512][e=128]
#define U_PK    33554432ull
#define U_VP    41943040ull    // [b] flat [o=512][r=1024]
#define U_WV    50331648ull
#define U_WQK   50593792ull

__device__ __forceinline__ u16 f2bf(float f) {
    union { float f; unsigned u; } v; v.f = f;
    return (u16)((v.u + 0x7fffu + ((v.u >> 16) & 1u)) >> 16);
}
__device__ __forceinline__ float bf2f(u16 u) {
    union { unsigned u; float f; } v; v.u = ((unsigned)u) << 16;
    return v.f;
}
__device__ __forceinline__ void ld_async16(const u16* g, u16* l) {
    __builtin_amdgcn_global_load_lds(
        (const __attribute__((address_space(1))) void*)g,
        (__attribute__((address_space(3))) void*)l, 16, 0, 0);
}

// ---------------- K1: pool + transposes + weight prep (merged) ----------------
// blocks [0,8192): fused 3x3 avg+max pool + bf16 transposes (LDS-staged input).
// blocks [8192,8576): float4->ushort4 casts of Wv/Wqk.
// blocks [8576,8832): Wp transpose tiles.
__global__ __launch_bounds__(256) void pool_prep(const float* __restrict__ x,
                                                 float* __restrict__ qp,
                                                 u16* __restrict__ qpT_v,
                                                 u16* __restrict__ qpT_p,
                                                 u16* __restrict__ kpT_p,
                                                 const float* __restrict__ Wv,
                                                 const float* __restrict__ Wqk,
                                                 const float* __restrict__ Wp,
                                                 u16* __restrict__ Wv_bf,
                                                 u16* __restrict__ Wqk_bf,
                                                 float* __restrict__ WpT) {
    __shared__ __align__(16) float Xs[9216];   // [ch=32][288] (3 contiguous rows)
    __shared__ float Tq[32][33], Tk[32][33];
    const int tid = threadIdx.x;
    const int blk = blockIdx.x;
    if (blk >= 8192) {
        const int pb = blk - 8192;
        if (pb < 384) {
            int idx = (pb * 256 + tid) * 4;
            const float* src; u16* dst; int off;
            if (idx < 262144) { src = Wv; dst = Wv_bf; off = idx; }
            else              { src = Wqk; dst = Wqk_bf; off = idx - 262144; }
            float4 v = *(const float4*)(src + off);
            ushort4v o; o.x = f2bf(v.x); o.y = f2bf(v.y); o.z = f2bf(v.z); o.w = f2bf(v.w);
            *(ushort4v*)(dst + off) = o;
        } else {
            int bb = pb - 384;
            int x0 = (bb & 15) * 32, y0 = (bb >> 4) * 32;
            int tx = tid & 31, ty = tid >> 5;
            #pragma unroll
            for (int it = 0; it < 4; ++it)
                Tq[ty + it * 8][tx] = Wp[(size_t)(y0 + ty + it * 8) * 512 + x0 + tx];
            __syncthreads();
            #pragma unroll
            for (int it = 0; it < 4; ++it)
                WpT[(size_t)(x0 + ty + it * 8) * 512 + y0 + tx] = Tq[tx][ty + it * 8];
        }
        return;
    }
    const int i  = blk & 31;              // pooled row 0..31
    const int c0 = ((blk >> 5) & 15) * 32; // channel base
    const int b  = blk >> 9;
    {   // stage: 2304 float4, fully coalesced (each channel's 3 rows contiguous)
        const float* xb = x + (size_t)b * 4718592 + (size_t)c0 * 9216 + (3 * i) * 96;
        float4* Xs4 = (float4*)Xs;
        #pragma unroll
        for (int it = 0; it < 9; ++it) {
            int f = tid + it * 256;          // 0..2303
            int cl = f / 72;                 // channel 0..31
            int rem = f - cl * 72;           // float4 within 288-float segment
            Xs4[f] = *(const float4*)(xb + (size_t)cl * 9216 + rem * 4);
        }
    }
    __syncthreads();
    const int j = tid & 31, cg = tid >> 5;
    #pragma unroll
    for (int p = 0; p < 4; ++p) {
        int cl = p * 8 + cg;
        const float* px = Xs + cl * 288 + 3 * j;   // stride-3 lanes: gcd(3,32)=1, no conflict
        float s = 0.f, mx = -INFINITY;
        #pragma unroll
        for (int di = 0; di < 3; ++di)
            #pragma unroll
            for (int dj = 0; dj < 3; ++dj) {
                float v = px[di * 96 + dj];
                s += v; mx = fmaxf(mx, v);
            }
        float q = s * (1.f / 9.f);
        Tq[cl][j] = q; Tk[cl][j] = mx;
        qp[(size_t)b * 524288 + (size_t)(c0 + cl) * 1024 + i * 32 + j] = q;
    }
    __syncthreads();
    const int cl = tid & 31, jq = tid >> 5;
    const int rh = i >> 4;
    const int s2 = (c0 + cl) * 2 + rh;
    #pragma unroll
    for (int jj = 0; jj < 4; ++jj) {
        int jw = jq + jj * 8;
        int rr = i * 32 + jw;
        int cc = rr & 511;
        u16 qb = f2bf(Tq[cl][jw]);
        u16 kb = f2bf(Tk[cl][jw]);
        qpT_v[(size_t)b * 524288 + (size_t)rr * 512 + c0 + cl] = qb;
        qpT_p[(size_t)b * 524288 + (size_t)cc * 1024 + s2] = qb;
        kpT_p[(size_t)b * 524288 + (size_t)cc * 1024 + s2] = kb;
    }
}

// ---------------- shared MFMA 128x128 BT-GEMM body (m97 structure) ----------------
__device__ __forceinline__ void gemm_bt_body(const u16* __restrict__ A, int ldA,
                                             const u16* __restrict__ B, int ldB, int K,
                                             u16* As, u16* Bs, floatx4 (&acc)[4][4]) {
    const int tid = threadIdx.x;
    const int lane = tid & 63;
    const int wv = tid >> 6;
    const int wm = (wv & 1) * 64, wn = (wv >> 1) * 64;
    const u16* ga0 = A + (size_t)(tid >> 2) * ldA + (tid & 3) * 8;
    const u16* ga1 = A + (size_t)((tid >> 2) + 64) * ldA + (tid & 3) * 8;
    const u16* gb0 = B + (size_t)(tid >> 2) * ldB + (tid & 3) * 8;
    const u16* gb1 = B + (size_t)((tid >> 2) + 64) * ldB + (tid & 3) * 8;
    u16* la0 = As + tid * 8;
    u16* la1 = As + (tid + 256) * 8;
    u16* lb0 = Bs + tid * 8;
    u16* lb1 = Bs + (tid + 256) * 8;
    const int arow = (lane & 15) * 32 + (lane >> 4) * 8;
    for (int k0 = 0; k0 < K; k0 += 32) {
        ld_async16(ga0 + k0, la0);
        ld_async16(ga1 + k0, la1);
        ld_async16(gb0 + k0, lb0);
        ld_async16(gb1 + k0, lb1);
        __syncthreads();
        bf16x8 af[4], bfr[4];
        #pragma unroll
        for (int i = 0; i < 4; ++i)
            af[i] = *(const bf16x8*)&As[(wm + i * 16) * 32 + arow];
        #pragma unroll
        for (int j = 0; j < 4; ++j)
            bfr[j] = *(const bf16x8*)&Bs[(wn + j * 16) * 32 + arow];
        #pragma unroll
        for (int i = 0; i < 4; ++i)
            #pragma unroll
            for (int j = 0; j < 4; ++j)
                acc[i][j] = __builtin_amdgcn_mfma_f32_16x16x32_bf16(af[i], bfr[j], acc[i][j], 0, 0, 0);
        __syncthreads();
    }
}

// ---------------- K2: merged GEMMs (vpool + proj) in ONE launch ----------------
__global__ __launch_bounds__(256) void gemms_mfma(const u16* __restrict__ Wv_bf,
                                                  const float* __restrict__ bv,
                                                  const u16* __restrict__ qpT_v,
                                                  u16* __restrict__ vp_bf,
                                                  const u16* __restrict__ qpT_p,
                                                  const u16* __restrict__ kpT_p,
                                                  const u16* __restrict__ Wqk_bf,
                                                  const float* __restrict__ bqk,
                                                  u16* __restrict__ pq_bf,
                                                  u16* __restrict__ pk_bf) {
    __shared__ __align__(16) u16 As[4096], Bs[4096];
    floatx4 acc[4][4] = {};
    const int tid = threadIdx.x, lane = tid & 63, wv = tid >> 6;
    const int wm = (wv & 1) * 64, wn = (wv >> 1) * 64, col = lane & 15, quad = lane >> 4;
    const int blk = blockIdx.x;
    if (blk < 512) {
        const int n0 = (blk & 7) * 128, m0 = ((blk >> 3) & 3) * 128, b = blk >> 5;
        gemm_bt_body(Wv_bf + (size_t)m0 * 512, 512,
                     qpT_v + (size_t)b * 524288 + (size_t)n0 * 512, 512, 512, As, Bs, acc);
        u16* outb = vp_bf + (size_t)b * 524288;
        #pragma unroll
        for (int i = 0; i < 4; ++i)
            #pragma unroll
            for (int r = 0; r < 4; ++r) {
                int m = m0 + wm + i * 16 + quad * 4 + r;
                float bias = bv[m];
                #pragma unroll
                for (int j = 0; j < 4; ++j) {
                    int n = n0 + wn + j * 16 + col;
                    outb[(size_t)m * 1024 + n] = f2bf(acc[i][j][r] + bias);
                }
            }
    } else {
        const int blk2 = blk - 512;
        const int m0 = (blk2 & 3) * 128;
        const int z = blk2 >> 2;
        const int b = z >> 4, h = (z >> 1) & 7, src = z & 1;
        const u16* P = (src ? kpT_p : qpT_p) + (size_t)b * 524288 + (size_t)m0 * 1024 + h * 128;
        gemm_bt_body(P, 1024, Wqk_bf + h * 16384, 128, 128, As, Bs, acc);
        u16* outp = (src ? pk_bf : pq_bf) + (size_t)(b * 8 + h) * 65536 + (size_t)m0 * 128;
        #pragma unroll
        for (int i = 0; i < 4; ++i)
            #pragma unroll
            for (int r = 0; r < 4; ++r) {
                int m = wm + i * 16 + quad * 4 + r;
                #pragma unroll
                for (int j = 0; j < 4; ++j) {
                    int n = wn + j * 16 + col;
                    outp[(size_t)m * 128 + n] = f2bf(acc[i][j][r] + bqk[h * 128 + n]);
                }
            }
    }
}

// ---------------- K3: fused kbar -> mrow -> gate (per bh) ----------------
__global__ __launch_bounds__(256) void gate_fused(const u16* __restrict__ pq_bf,
                                                  const u16* __restrict__ pk_bf,
                                                  const float* __restrict__ WpT,
                                                  const float* __restrict__ bp,
                                                  float* __restrict__ ipw) {
    __shared__ float red[16][128];   // rowgroup partials
    __shared__ float kb[128];
    __shared__ float ms[512];
    __shared__ float part[4][512];
    const int bh = blockIdx.x, tid = threadIdx.x;
    const u16* pkb = pk_bf + (size_t)bh * 65536;
    const u16* pqb = pq_bf + (size_t)bh * 65536;
    {   // kbar partials: 16 d-chunks x 16 rowgroups, bf16x8 loads
        const int dc = tid & 15, rg = tid >> 4;
        float a[8] = {};
        const u16* p = pkb + (size_t)rg * 4096 + dc * 8;
        #pragma unroll 8
        for (int r = 0; r < 32; ++r) {
            bf16x8 v = *(const bf16x8*)(p + (size_t)r * 128);
            #pragma unroll
            for (int k = 0; k < 8; ++k) a[k] += bf2f((u16)v[k]);
        }
        #pragma unroll
        for (int k = 0; k < 8; ++k) red[rg][dc * 8 + k] = a[k];
    }
    __syncthreads();
    if (tid < 128) {
        float s = 0.f;
        #pragma unroll
        for (int g = 0; g < 16; ++g) s += red[g][tid];
        kb[tid] = s * (1.f / 512.f);
    }
    __syncthreads();
    // mrow: ms[cc] = dot(pq[cc][:], kb)
    for (int cc = tid; cc < 512; cc += 256) {
        const u16* q = pqb + (size_t)cc * 128;
        float s = 0.f;
        #pragma unroll
        for (int ch = 0; ch < 16; ++ch) {
            bf16x8 v = *(const bf16x8*)(q + ch * 8);
            #pragma unroll
            for (int k = 0; k < 8; ++k) s += bf2f((u16)v[k]) * kb[ch * 8 + k];
        }
        ms[cc] = s;
    }
    __syncthreads();
    {   // gate matvec: 4-way c-split across waves, float4 loads, 8 cols/thread
        const int g = tid >> 6, l = tid & 63;
        const int c2 = l * 8;
        float a[8] = {};
        const int cb = g * 128;
        #pragma unroll 4
        for (int c = cb; c < cb + 128; ++c) {
            float m = ms[c];
            const float* w = WpT + (size_t)c * 512 + c2;
            float4 w0 = *(const float4*)w;
            float4 w1 = *(const float4*)(w + 4);
            a[0] += m * w0.x; a[1] += m * w0.y; a[2] += m * w0.z; a[3] += m * w0.w;
            a[4] += m * w1.x; a[5] += m * w1.y; a[6] += m * w1.z; a[7] += m * w1.w;
        }
        #pragma unroll
        for (int k = 0; k < 8; ++k) part[g][c2 + k] = a[k];
    }
    __syncthreads();
    {
        const int c2 = tid * 2;
        float a0 = bp[c2]     + part[0][c2]     + part[1][c2]     + part[2][c2]     + part[3][c2];
        float a1 = bp[c2 + 1] + part[0][c2 + 1] + part[1][c2 + 1] + part[2][c2 + 1] + part[3][c2 + 1];
        float p0 = 1.f / (1.f + __expf(-a0));
        float p1 = 1.f / (1.f + __expf(-a1));
        ipw[bh * 512 + c2]     = exp2f(-7.f * (0.5f + p0));   // 128^-(0.5+p)
        ipw[bh * 512 + c2 + 1] = exp2f(-7.f * (0.5f + p1));
    }
}

// ---------------- K4: flash-fused scores->exp->rowsum->PV->residual (restructured) ----------------
// Q fragments in registers (loaded once); K/V tiles staged as full 128x128 with ONE barrier
// each (8x global_load_lds dwordx4, XOR-swizzled source + swizzled ds_read to kill the
// row-major-[*][128] 16-way bank conflict). Barriers per block: 72 -> 16.
__global__ __launch_bounds__(256, 2) void flash_mfma(const u16* __restrict__ pq_bf,
                                                     const u16* __restrict__ pk_bf,
                                                     const u16* __restrict__ vp_bf,
                                                     const float* __restrict__ ipw,
                                                     const float* __restrict__ qp,
                                                     float* __restrict__ outp,
                                                     const int* __restrict__ wgt) {
    __shared__ __align__(16) u16 Stg[16384];      // 128 rows x 128 k (32 KB)
    __shared__ __align__(16) u16 Et[128 * 136];   // exp(scores) bf16 [c][e]
    __shared__ float rsS[128];
    __shared__ float ipwS[128];
    const int tid = threadIdx.x, lane = tid & 63, wv = tid >> 6;
    const int wm = (wv & 1) * 64, wn = (wv >> 1) * 64, col = lane & 15, quad = lane >> 4;
    const int bh = blockIdx.y, b = bh >> 3, h = bh & 7;
    const int m0 = blockIdx.x * 128;
    if (tid < 128) { rsS[tid] = 0.f; ipwS[tid] = ipw[bh * 512 + m0 + tid]; }
    const u16* Aq = pq_bf + (size_t)bh * 65536 + (size_t)m0 * 128;
    const u16* Bk = pk_bf + (size_t)bh * 65536;
    const u16* Av = vp_bf + (size_t)b * 524288 + (size_t)h * 65536;
    // Q fragments in registers: afq[i][kk] covers rows (wm+i*16+col), k = kk*32+quad*8
    bf16x8 afq[4][4];
    #pragma unroll
    for (int i = 0; i < 4; ++i)
        #pragma unroll
        for (int kk = 0; kk < 4; ++kk)
            afq[i][kk] = *(const bf16x8*)&Aq[(size_t)(wm + i * 16 + col) * 128 + kk * 32 + quad * 8];
    // staging constants: linear LDS dest (tid*16B), pre-swizzled global source.
    // row = it*16 + (tid>>4); since 16%8==0, row&7 == (tid>>4)&7 (it-invariant).
    const int srow16 = tid >> 4;
    const int soff = ((((tid & 15) << 4) ^ ((srow16 & 7) << 4)) >> 1);  // u16 within 256B row
    u16* ldst = Stg + tid * 8;
    const int cswz = (col & 7) << 3;   // u16-index XOR for swizzled ds_read
    floatx4 accP[4][4] = {};
    __syncthreads();

    for (int n0 = 0; n0 < 512; n0 += 128) {
        // ---- stage K tile [e=n0..n0+127][k=128] ----
        #pragma unroll
        for (int it = 0; it < 8; ++it)
            ld_async16(Bk + (size_t)(n0 + it * 16 + srow16) * 128 + soff, ldst + it * 2048);
        __syncthreads();
        // ---- scores: regs(Q) x LDS(K), 64 MFMA per wave ----
        floatx4 accS[4][4] = {};
        #pragma unroll
        for (int kk = 0; kk < 4; ++kk) {
            bf16x8 bfr[4];
            #pragma unroll
            for (int j = 0; j < 4; ++j)
                bfr[j] = *(const bf16x8*)&Stg[(wn + j * 16 + col) * 128 + ((kk * 32 + quad * 8) ^ cswz)];
            #pragma unroll
            for (int i = 0; i < 4; ++i)
                #pragma unroll
                for (int j = 0; j < 4; ++j)
                    accS[i][j] = __builtin_amdgcn_mfma_f32_16x16x32_bf16(afq[i][kk], bfr[j], accS[i][j], 0, 0, 0);
        }
        // ---- epilogue: exp -> Et (LDS), rowsum -> rsS ----
        #pragma unroll
        for (int i = 0; i < 4; ++i)
            #pragma unroll
            for (int r = 0; r < 4; ++r) {
                int ml = wm + i * 16 + quad * 4 + r;
                float sc = ipwS[ml];
                float p = 0.f;
                #pragma unroll
                for (int j = 0; j < 4; ++j) {
                    float e = __expf(accS[i][j][r] * sc);
                    p += e;
                    Et[ml * 136 + wn + j * 16 + col] = f2bf(e);
                }
                #pragma unroll
                for (int o = 8; o; o >>= 1) p += __shfl_xor(p, o);
                if (col == 0) atomicAdd(&rsS[ml], p);
            }
        __syncthreads();   // Et ready; all K-tile reads done
        // ---- stage V tile [d=0..127][e=n0..n0+127] ----
        #pragma unroll
        for (int it = 0; it < 8; ++it)
            ld_async16(Av + (size_t)(it * 16 + srow16) * 512 + n0 + soff, ldst + it * 2048);
        __syncthreads();
        // ---- PV: LDS(V) x LDS(Et), 64 MFMA per wave ----
        #pragma unroll
        for (int kk = 0; kk < 4; ++kk) {
            bf16x8 av[4], et[4];
            #pragma unroll
            for (int i = 0; i < 4; ++i)
                av[i] = *(const bf16x8*)&Stg[(wm + i * 16 + col) * 128 + ((kk * 32 + quad * 8) ^ cswz)];
            #pragma unroll
            for (int j = 0; j < 4; ++j)
                et[j] = *(const bf16x8*)&Et[(wn + j * 16 + col) * 136 + kk * 32 + quad * 8];
            #pragma unroll
            for (int i = 0; i < 4; ++i)
                #pragma unroll
                for (int j = 0; j < 4; ++j)
                    accP[i][j] = __builtin_amdgcn_mfma_f32_16x16x32_bf16(av[i], et[j], accP[i][j], 0, 0, 0);
        }
        __syncthreads();   // Stg + Et reusable next n0
    }
    const float mult = 1.f + (float)wgt[0];
    #pragma unroll
    for (int j = 0; j < 4; ++j) {
        int nl = wn + j * 16 + col;                 // c local
        float inv = mult / rsS[nl];
        #pragma unroll
        for (int i = 0; i < 4; ++i)
            #pragma unroll
            for (int r = 0; r < 4; ++r) {
                int d = wm + i * 16 + quad * 4 + r;
                size_t o = (size_t)b * 524288 + (size_t)(h * 128 + d) * 512 + m0 + nl;
                outp[o] = qp[o] + accP[i][j][r] * inv;
            }
    }
}

extern "C" void kernel_launch(void* const* d_in, const int* in_sizes, int n_in,
                              void* d_out, int out_size, void* d_ws, size_t ws_size,
                              hipStream_t stream) {
    const float* x   = (const float*)d_in[0];
    const float* Wqk = (const float*)d_in[1];
    const float* bqk = (const float*)d_in[2];
    const float* Wp  = (const float*)d_in[3];
    const float* bp  = (const float*)d_in[4];
    const float* Wv  = (const float*)d_in[5];
    const float* bv  = (const float*)d_in[6];
    const int*   wgt = (const int*)d_in[7];
    float* out = (float*)d_out;

    float* ws = (float*)d_ws;
    float* qp  = ws + F_QP;
    float* ipw = ws + F_IPW;
    float* WpT = ws + F_WPT;
    u16* ub = (u16*)(ws + F_END);
    u16* qpT_v  = ub + U_QPT_V;
    u16* qpT_p  = ub + U_QPT_P;
    u16* kpT_p  = ub + U_KPT_P;
    u16* pq_bf  = ub + U_PQ;
    u16* pk_bf  = ub + U_PK;
    u16* vp_bf  = ub + U_VP;
    u16* Wv_bf  = ub + U_WV;
    u16* Wqk_bf = ub + U_WQK;

    pool_prep<<<8832, 256, 0, stream>>>(x, qp, qpT_v, qpT_p, kpT_p,
                                        Wv, Wqk, Wp, Wv_bf, Wqk_bf, WpT);
    gemms_mfma<<<1536, 256, 0, stream>>>(Wv_bf, bv, qpT_v, vp_bf,
                                         qpT_p, kpT_p, Wqk_bf, bqk, pq_bf, pk_bf);
    gate_fused<<<128, 256, 0, stream>>>(pq_bf, pk_bf, WpT, bp, ipw);
    flash_mfma<<<dim3(4, 128), 256, 0, stream>>>(pq_bf, pk_bf, vp_bf, ipw, qp, out, wgt);
}

// Round 4
// 527.720 us; speedup vs baseline: 1.1338x; 1.0121x over previous
//
#include <hip/hip_runtime.h>
#include <math.h>

// Problem: B=16, C=512, R=32, PS=3, HN=8, D=128, H=W=96.
typedef unsigned short u16;
typedef short bf16x8 __attribute__((ext_vector_type(8)));
typedef float floatx4 __attribute__((ext_vector_type(4)));
typedef unsigned short ushort4v __attribute__((ext_vector_type(4)));

// ---- workspace layout ----
// floats:
#define F_QP   0ull            // [b][c=512][r=1024] fp32 pooled avg (residual + src)
#define F_IPW  8388608ull      // [bh][512]
#define F_WPT  8454144ull      // WpT [c][c2] 512x512
#define F_END  8716288ull
// ushorts (base = (u16*)(ws + F_END)):
#define U_QPT_V 0ull           // [b][r=1024][c=512]
#define U_QPT_P 8388608ull     // [b][cc=512][s=1024]
#define U_KPT_P 16777216ull
#define U_PQ    25165824ull    // [bh][c=512][e=128]
#define U_PK    33554432ull
#define U_VP    41943040ull    // [b] flat [o=512][r=1024]
#define U_WV    50331648ull
#define U_WQK   50593792ull

__device__ __forceinline__ u16 f2bf(float f) {
    union { float f; unsigned u; } v; v.f = f;
    return (u16)((v.u + 0x7fffu + ((v.u >> 16) & 1u)) >> 16);
}
__device__ __forceinline__ float bf2f(u16 u) {
    union { unsigned u; float f; } v; v.u = ((unsigned)u) << 16;
    return v.f;
}
__device__ __forceinline__ void ld_async16(const u16* g, u16* l) {
    __builtin_amdgcn_global_load_lds(
        (const __attribute__((address_space(1))) void*)g,
        (__attribute__((address_space(3))) void*)l, 16, 0, 0);
}

// ---------------- K1: pool + transposes + weight prep (merged) ----------------
__global__ __launch_bounds__(256) void pool_prep(const float* __restrict__ x,
                                                 float* __restrict__ qp,
                                                 u16* __restrict__ qpT_v,
                                                 u16* __restrict__ qpT_p,
                                                 u16* __restrict__ kpT_p,
                                                 const float* __restrict__ Wv,
                                                 const float* __restrict__ Wqk,
                                                 const float* __restrict__ Wp,
                                                 u16* __restrict__ Wv_bf,
                                                 u16* __restrict__ Wqk_bf,
                                                 float* __restrict__ WpT) {
    __shared__ __align__(16) float Xs[9216];   // [ch=32][288] (3 contiguous rows)
    __shared__ float Tq[32][33], Tk[32][33];
    const int tid = threadIdx.x;
    const int blk = blockIdx.x;
    if (blk >= 8192) {
        const int pb = blk - 8192;
        if (pb < 384) {
            int idx = (pb * 256 + tid) * 4;
            const float* src; u16* dst; int off;
            if (idx < 262144) { src = Wv; dst = Wv_bf; off = idx; }
            else              { src = Wqk; dst = Wqk_bf; off = idx - 262144; }
            float4 v = *(const float4*)(src + off);
            ushort4v o; o.x = f2bf(v.x); o.y = f2bf(v.y); o.z = f2bf(v.z); o.w = f2bf(v.w);
            *(ushort4v*)(dst + off) = o;
        } else {
            int bb = pb - 384;
            int x0 = (bb & 15) * 32, y0 = (bb >> 4) * 32;
            int tx = tid & 31, ty = tid >> 5;
            #pragma unroll
            for (int it = 0; it < 4; ++it)
                Tq[ty + it * 8][tx] = Wp[(size_t)(y0 + ty + it * 8) * 512 + x0 + tx];
            __syncthreads();
            #pragma unroll
            for (int it = 0; it < 4; ++it)
                WpT[(size_t)(x0 + ty + it * 8) * 512 + y0 + tx] = Tq[tx][ty + it * 8];
        }
        return;
    }
    const int i  = blk & 31;              // pooled row 0..31
    const int c0 = ((blk >> 5) & 15) * 32; // channel base
    const int b  = blk >> 9;
    {   // stage: 2304 float4, fully coalesced
        const float* xb = x + (size_t)b * 4718592 + (size_t)c0 * 9216 + (3 * i) * 96;
        float4* Xs4 = (float4*)Xs;
        #pragma unroll
        for (int it = 0; it < 9; ++it) {
            int f = tid + it * 256;          // 0..2303
            int cl = f / 72;                 // channel 0..31
            int rem = f - cl * 72;           // float4 within 288-float segment
            Xs4[f] = *(const float4*)(xb + (size_t)cl * 9216 + rem * 4);
        }
    }
    __syncthreads();
    const int j = tid & 31, cg = tid >> 5;
    #pragma unroll
    for (int p = 0; p < 4; ++p) {
        int cl = p * 8 + cg;
        const float* px = Xs + cl * 288 + 3 * j;
        float s = 0.f, mx = -INFINITY;
        #pragma unroll
        for (int di = 0; di < 3; ++di)
            #pragma unroll
            for (int dj = 0; dj < 3; ++dj) {
                float v = px[di * 96 + dj];
                s += v; mx = fmaxf(mx, v);
            }
        float q = s * (1.f / 9.f);
        Tq[cl][j] = q; Tk[cl][j] = mx;
        qp[(size_t)b * 524288 + (size_t)(c0 + cl) * 1024 + i * 32 + j] = q;
    }
    __syncthreads();
    const int cl = tid & 31, jq = tid >> 5;
    const int rh = i >> 4;
    const int s2 = (c0 + cl) * 2 + rh;
    #pragma unroll
    for (int jj = 0; jj < 4; ++jj) {
        int jw = jq + jj * 8;
        int rr = i * 32 + jw;
        int cc = rr & 511;
        u16 qb = f2bf(Tq[cl][jw]);
        u16 kb = f2bf(Tk[cl][jw]);
        qpT_v[(size_t)b * 524288 + (size_t)rr * 512 + c0 + cl] = qb;
        qpT_p[(size_t)b * 524288 + (size_t)cc * 1024 + s2] = qb;
        kpT_p[(size_t)b * 524288 + (size_t)cc * 1024 + s2] = kb;
    }
}

// ---------------- shared MFMA 128x128 BT-GEMM body (m97 structure) ----------------
__device__ __forceinline__ void gemm_bt_body(const u16* __restrict__ A, int ldA,
                                             const u16* __restrict__ B, int ldB, int K,
                                             u16* As, u16* Bs, floatx4 (&acc)[4][4]) {
    const int tid = threadIdx.x;
    const int lane = tid & 63;
    const int wv = tid >> 6;
    const int wm = (wv & 1) * 64, wn = (wv >> 1) * 64;
    const u16* ga0 = A + (size_t)(tid >> 2) * ldA + (tid & 3) * 8;
    const u16* ga1 = A + (size_t)((tid >> 2) + 64) * ldA + (tid & 3) * 8;
    const u16* gb0 = B + (size_t)(tid >> 2) * ldB + (tid & 3) * 8;
    const u16* gb1 = B + (size_t)((tid >> 2) + 64) * ldB + (tid & 3) * 8;
    u16* la0 = As + tid * 8;
    u16* la1 = As + (tid + 256) * 8;
    u16* lb0 = Bs + tid * 8;
    u16* lb1 = Bs + (tid + 256) * 8;
    const int arow = (lane & 15) * 32 + (lane >> 4) * 8;
    for (int k0 = 0; k0 < K; k0 += 32) {
        ld_async16(ga0 + k0, la0);
        ld_async16(ga1 + k0, la1);
        ld_async16(gb0 + k0, lb0);
        ld_async16(gb1 + k0, lb1);
        __syncthreads();
        bf16x8 af[4], bfr[4];
        #pragma unroll
        for (int i = 0; i < 4; ++i)
            af[i] = *(const bf16x8*)&As[(wm + i * 16) * 32 + arow];
        #pragma unroll
        for (int j = 0; j < 4; ++j)
            bfr[j] = *(const bf16x8*)&Bs[(wn + j * 16) * 32 + arow];
        #pragma unroll
        for (int i = 0; i < 4; ++i)
            #pragma unroll
            for (int j = 0; j < 4; ++j)
                acc[i][j] = __builtin_amdgcn_mfma_f32_16x16x32_bf16(af[i], bfr[j], acc[i][j], 0, 0, 0);
        __syncthreads();
    }
}

// ---------------- K2: merged GEMMs (vpool + proj) in ONE launch ----------------
__global__ __launch_bounds__(256) void gemms_mfma(const u16* __restrict__ Wv_bf,
                                                  const float* __restrict__ bv,
                                                  const u16* __restrict__ qpT_v,
                                                  u16* __restrict__ vp_bf,
                                                  const u16* __restrict__ qpT_p,
                                                  const u16* __restrict__ kpT_p,
                                                  const u16* __restrict__ Wqk_bf,
                                                  const float* __restrict__ bqk,
                                                  u16* __restrict__ pq_bf,
                                                  u16* __restrict__ pk_bf) {
    __shared__ __align__(16) u16 As[4096], Bs[4096];
    floatx4 acc[4][4] = {};
    const int tid = threadIdx.x, lane = tid & 63, wv = tid >> 6;
    const int wm = (wv & 1) * 64, wn = (wv >> 1) * 64, col = lane & 15, quad = lane >> 4;
    const int blk = blockIdx.x;
    if (blk < 512) {
        const int n0 = (blk & 7) * 128, m0 = ((blk >> 3) & 3) * 128, b = blk >> 5;
        gemm_bt_body(Wv_bf + (size_t)m0 * 512, 512,
                     qpT_v + (size_t)b * 524288 + (size_t)n0 * 512, 512, 512, As, Bs, acc);
        u16* outb = vp_bf + (size_t)b * 524288;
        #pragma unroll
        for (int i = 0; i < 4; ++i)
            #pragma unroll
            for (int r = 0; r < 4; ++r) {
                int m = m0 + wm + i * 16 + quad * 4 + r;
                float bias = bv[m];
                #pragma unroll
                for (int j = 0; j < 4; ++j) {
                    int n = n0 + wn + j * 16 + col;
                    outb[(size_t)m * 1024 + n] = f2bf(acc[i][j][r] + bias);
                }
            }
    } else {
        const int blk2 = blk - 512;
        const int m0 = (blk2 & 3) * 128;
        const int z = blk2 >> 2;
        const int b = z >> 4, h = (z >> 1) & 7, src = z & 1;
        const u16* P = (src ? kpT_p : qpT_p) + (size_t)b * 524288 + (size_t)m0 * 1024 + h * 128;
        gemm_bt_body(P, 1024, Wqk_bf + h * 16384, 128, 128, As, Bs, acc);
        u16* outp = (src ? pk_bf : pq_bf) + (size_t)(b * 8 + h) * 65536 + (size_t)m0 * 128;
        #pragma unroll
        for (int i = 0; i < 4; ++i)
            #pragma unroll
            for (int r = 0; r < 4; ++r) {
                int m = wm + i * 16 + quad * 4 + r;
                #pragma unroll
                for (int j = 0; j < 4; ++j) {
                    int n = wn + j * 16 + col;
                    outp[(size_t)m * 128 + n] = f2bf(acc[i][j][r] + bqk[h * 128 + n]);
                }
            }
    }
}

// ---------------- K3: fused kbar -> mrow -> gate (grid 256: bh x c2-half) ----------------
__global__ __launch_bounds__(256) void gate_fused(const u16* __restrict__ pq_bf,
                                                  const u16* __restrict__ pk_bf,
                                                  const float* __restrict__ WpT,
                                                  const float* __restrict__ bp,
                                                  float* __restrict__ ipw) {
    __shared__ float red[16][128];   // rowgroup partials
    __shared__ float kb[128];
    __shared__ float ms[512];
    __shared__ float part[4][256];
    const int blk = blockIdx.x, tid = threadIdx.x;
    const int bh = blk >> 1, half = blk & 1;
    const u16* pkb = pk_bf + (size_t)bh * 65536;
    const u16* pqb = pq_bf + (size_t)bh * 65536;
    {   // kbar partials: 16 d-chunks x 16 rowgroups, bf16x8 loads
        const int dc = tid & 15, rg = tid >> 4;
        float a[8] = {};
        const u16* p = pkb + (size_t)rg * 4096 + dc * 8;
        #pragma unroll 8
        for (int r = 0; r < 32; ++r) {
            bf16x8 v = *(const bf16x8*)(p + (size_t)r * 128);
            #pragma unroll
            for (int k = 0; k < 8; ++k) a[k] += bf2f((u16)v[k]);
        }
        #pragma unroll
        for (int k = 0; k < 8; ++k) red[rg][dc * 8 + k] = a[k];
    }
    __syncthreads();
    if (tid < 128) {
        float s = 0.f;
        #pragma unroll
        for (int g = 0; g < 16; ++g) s += red[g][tid];
        kb[tid] = s * (1.f / 512.f);
    }
    __syncthreads();
    // mrow: ms[cc] = dot(pq[cc][:], kb)
    for (int cc = tid; cc < 512; cc += 256) {
        const u16* q = pqb + (size_t)cc * 128;
        float s = 0.f;
        #pragma unroll
        for (int ch = 0; ch < 16; ++ch) {
            bf16x8 v = *(const bf16x8*)(q + ch * 8);
            #pragma unroll
            for (int k = 0; k < 8; ++k) s += bf2f((u16)v[k]) * kb[ch * 8 + k];
        }
        ms[cc] = s;
    }
    __syncthreads();
    {   // gate matvec for c2 in [half*256, half*256+256): 4-way c-split over waves
        const int g = tid >> 6, l = tid & 63;
        const int lc = l * 4;
        const int c2 = half * 256 + lc;
        float a[4] = {};
        const int cb = g * 128;
        #pragma unroll 4
        for (int c = cb; c < cb + 128; ++c) {
            float m = ms[c];
            float4 w = *(const float4*)&WpT[(size_t)c * 512 + c2];
            a[0] += m * w.x; a[1] += m * w.y; a[2] += m * w.z; a[3] += m * w.w;
        }
        #pragma unroll
        for (int k = 0; k < 4; ++k) part[g][lc + k] = a[k];
    }
    __syncthreads();
    {
        const int lc = tid;
        if (lc < 256) {
            const int c2 = half * 256 + lc;
            float a = bp[c2] + part[0][lc] + part[1][lc] + part[2][lc] + part[3][lc];
            float pg = 1.f / (1.f + __expf(-a));
            ipw[bh * 512 + c2] = exp2f(-7.f * (0.5f + pg));   // 128^-(0.5+p)
        }
    }
}

// ---------------- K4: flash-fused scores->exp->rowsum->PV->residual ----------------
// v3: rowsum in per-thread registers (one final butterfly); V-tile loads issued
// under the exp/Et epilogue; next K-tile issued right after the post-PV barrier.
__global__ __launch_bounds__(256, 2) void flash_mfma(const u16* __restrict__ pq_bf,
                                                     const u16* __restrict__ pk_bf,
                                                     const u16* __restrict__ vp_bf,
                                                     const float* __restrict__ ipw,
                                                     const float* __restrict__ qp,
                                                     float* __restrict__ outp,
                                                     const int* __restrict__ wgt) {
    __shared__ __align__(16) u16 Stg[16384];      // 128 rows x 128 k (32 KB)
    __shared__ __align__(16) u16 Et[128 * 136];   // exp(scores) bf16 [c][e]
    __shared__ float rsP[2][128];
    __shared__ float ipwS[128];
    const int tid = threadIdx.x, lane = tid & 63, wv = tid >> 6;
    const int wm = (wv & 1) * 64, wn = (wv >> 1) * 64, col = lane & 15, quad = lane >> 4;
    const int wnh = wv >> 1;
    const int bh = blockIdx.y, b = bh >> 3, h = bh & 7;
    const int m0 = blockIdx.x * 128;
    if (tid < 128) ipwS[tid] = ipw[bh * 512 + m0 + tid];
    const u16* Aq = pq_bf + (size_t)bh * 65536 + (size_t)m0 * 128;
    const u16* Bk = pk_bf + (size_t)bh * 65536;
    const u16* Av = vp_bf + (size_t)b * 524288 + (size_t)h * 65536;
    // Q fragments in registers: afq[i][kk] covers rows (wm+i*16+col), k = kk*32+quad*8
    bf16x8 afq[4][4];
    #pragma unroll
    for (int i = 0; i < 4; ++i)
        #pragma unroll
        for (int kk = 0; kk < 4; ++kk)
            afq[i][kk] = *(const bf16x8*)&Aq[(size_t)(wm + i * 16 + col) * 128 + kk * 32 + quad * 8];
    // staging: linear LDS dest (tid*16B), pre-swizzled global source.
    const int srow16 = tid >> 4;
    const int soff = ((((tid & 15) << 4) ^ ((srow16 & 7) << 4)) >> 1);  // u16 within 256B row
    u16* ldst = Stg + tid * 8;
    const int cswz = (col & 7) << 3;   // u16-index XOR for swizzled ds_read
    floatx4 accP[4][4] = {};
    float rsum[4][4] = {{0.f, 0.f, 0.f, 0.f}, {0.f, 0.f, 0.f, 0.f},
                        {0.f, 0.f, 0.f, 0.f}, {0.f, 0.f, 0.f, 0.f}};
    // prologue: issue K tile for n0=0
    #pragma unroll
    for (int it = 0; it < 8; ++it)
        ld_async16(Bk + (size_t)(it * 16 + srow16) * 128 + soff, ldst + it * 2048);

    for (int n0 = 0; n0 < 512; n0 += 128) {
        __syncthreads();   // K tile landed (vmcnt drained); ipwS visible
        // ---- scores: regs(Q) x LDS(K), 64 MFMA per wave ----
        floatx4 accS[4][4] = {};
        #pragma unroll
        for (int kk = 0; kk < 4; ++kk) {
            bf16x8 bfr[4];
            #pragma unroll
            for (int j = 0; j < 4; ++j)
                bfr[j] = *(const bf16x8*)&Stg[(wn + j * 16 + col) * 128 + ((kk * 32 + quad * 8) ^ cswz)];
            #pragma unroll
            for (int i = 0; i < 4; ++i)
                #pragma unroll
                for (int j = 0; j < 4; ++j)
                    accS[i][j] = __builtin_amdgcn_mfma_f32_16x16x32_bf16(afq[i][kk], bfr[j], accS[i][j], 0, 0, 0);
        }
        __syncthreads();   // all K-tile ds_reads complete -> Stg free
        // ---- issue V tile loads; latency hides under the epilogue ----
        #pragma unroll
        for (int it = 0; it < 8; ++it)
            ld_async16(Av + (size_t)(it * 16 + srow16) * 512 + n0 + soff, ldst + it * 2048);
        // ---- epilogue: exp -> Et (LDS), rowsum -> registers ----
        #pragma unroll
        for (int i = 0; i < 4; ++i)
            #pragma unroll
            for (int r = 0; r < 4; ++r) {
                int ml = wm + i * 16 + quad * 4 + r;
                float sc = ipwS[ml];
                float p = 0.f;
                #pragma unroll
                for (int j = 0; j < 4; ++j) {
                    float e = __expf(accS[i][j][r] * sc);
                    p += e;
                    Et[ml * 136 + wn + j * 16 + col] = f2bf(e);
                }
                rsum[i][r] += p;
            }
        __syncthreads();   // V landed; Et visible
        // ---- PV: LDS(V) x LDS(Et), 64 MFMA per wave ----
        #pragma unroll
        for (int kk = 0; kk < 4; ++kk) {
            bf16x8 av[4], et[4];
            #pragma unroll
            for (int i = 0; i < 4; ++i)
                av[i] = *(const bf16x8*)&Stg[(wm + i * 16 + col) * 128 + ((kk * 32 + quad * 8) ^ cswz)];
            #pragma unroll
            for (int j = 0; j < 4; ++j)
                et[j] = *(const bf16x8*)&Et[(wn + j * 16 + col) * 136 + kk * 32 + quad * 8];
            #pragma unroll
            for (int i = 0; i < 4; ++i)
                #pragma unroll
                for (int j = 0; j < 4; ++j)
                    accP[i][j] = __builtin_amdgcn_mfma_f32_16x16x32_bf16(av[i], et[j], accP[i][j], 0, 0, 0);
        }
        __syncthreads();   // Stg + Et reads done
        if (n0 < 384) {    // issue next K tile (drained at loop-top barrier)
            #pragma unroll
            for (int it = 0; it < 8; ++it)
                ld_async16(Bk + (size_t)(n0 + 128 + it * 16 + srow16) * 128 + soff, ldst + it * 2048);
        }
    }
    // ---- final rowsum reduce: butterfly over 16 cols, LDS combine over wn-halves ----
    #pragma unroll
    for (int i = 0; i < 4; ++i)
        #pragma unroll
        for (int r = 0; r < 4; ++r) {
            float p = rsum[i][r];
            #pragma unroll
            for (int o = 8; o; o >>= 1) p += __shfl_xor(p, o);
            if (col == 0) rsP[wnh][wm + i * 16 + quad * 4 + r] = p;
        }
    __syncthreads();
    const float mult = 1.f + (float)wgt[0];
    #pragma unroll
    for (int j = 0; j < 4; ++j) {
        int nl = wn + j * 16 + col;                 // c local
        float inv = mult / (rsP[0][nl] + rsP[1][nl]);
        #pragma unroll
        for (int i = 0; i < 4; ++i)
            #pragma unroll
            for (int r = 0; r < 4; ++r) {
                int d = wm + i * 16 + quad * 4 + r;
                size_t o = (size_t)b * 524288 + (size_t)(h * 128 + d) * 512 + m0 + nl;
                outp[o] = qp[o] + accP[i][j][r] * inv;
            }
    }
}

extern "C" void kernel_launch(void* const* d_in, const int* in_sizes, int n_in,
                              void* d_out, int out_size, void* d_ws, size_t ws_size,
                              hipStream_t stream) {
    const float* x   = (const float*)d_in[0];
    const float* Wqk = (const float*)d_in[1];
    const float* bqk = (const float*)d_in[2];
    const float* Wp  = (const float*)d_in[3];
    const float* bp  = (const float*)d_in[4];
    const float* Wv  = (const float*)d_in[5];
    const float* bv  = (const float*)d_in[6];
    const int*   wgt = (const int*)d_in[7];
    float* out = (float*)d_out;

    float* ws = (float*)d_ws;
    float* qp  = ws + F_QP;
    float* ipw = ws + F_IPW;
    float* WpT = ws + F_WPT;
    u16* ub = (u16*)(ws + F_END);
    u16* qpT_v  = ub + U_QPT_V;
    u16* qpT_p  = ub + U_QPT_P;
    u16* kpT_p  = ub + U_KPT_P;
    u16* pq_bf  = ub + U_PQ;
    u16* pk_bf  = ub + U_PK;
    u16* vp_bf  = ub + U_VP;
    u16* Wv_bf  = ub + U_WV;
    u16* Wqk_bf = ub + U_WQK;

    pool_prep<<<8832, 256, 0, stream>>>(x, qp, qpT_v, qpT_p, kpT_p,
                                        Wv, Wqk, Wp, Wv_bf, Wqk_bf, WpT);
    gemms_mfma<<<1536, 256, 0, stream>>>(Wv_bf, bv, qpT_v, vp_bf,
                                         qpT_p, kpT_p, Wqk_bf, bqk, pq_bf, pk_bf);
    gate_fused<<<256, 256, 0, stream>>>(pq_bf, pk_bf, WpT, bp, ipw);
    flash_mfma<<<dim3(4, 128), 256, 0, stream>>>(pq_bf, pk_bf, vp_bf, ipw, qp, out, wgt);
}